// Round 9
// baseline (305.297 us; speedup 1.0000x reference)
//
#include <hip/hip_runtime.h>
#include <hip/hip_bf16.h>
#include <math.h>

#define D_SSM 512
#define D_STATE 16
#define CKPT_BASE 511     // first index of level 9
#define N_CKPT 512        // nodes at level 9
#define MPAD 16384

typedef __attribute__((ext_vector_type(8))) short short8;
typedef __attribute__((ext_vector_type(4))) float floatx4;

__device__ __forceinline__ unsigned short f2bf(float f) {
    unsigned int u = __float_as_uint(f);
    unsigned int r = (u + 0x7fffu + ((u >> 16) & 1u)) >> 16;
    return (unsigned short)r;
}
__device__ __forceinline__ float bf2f(unsigned short u) {
    return __uint_as_float(((unsigned int)u) << 16);
}
__device__ __forceinline__ void g2lds16(const void* g, void* l) {
    __builtin_amdgcn_global_load_lds(
        (const __attribute__((address_space(1))) void*)g,
        (__attribute__((address_space(3))) void*)l, 16, 0, 0);
}

// ---------------- prep: cast s/W_in/W_delta/W_B/W_C to bf16, compute lw ----------------
__global__ __launch_bounds__(256) void prep_kernel(
    const float* __restrict__ s, const float* __restrict__ w,
    const float* __restrict__ W_in, const float* __restrict__ W_delta,
    const float* __restrict__ W_B, const float* __restrict__ W_C,
    unsigned short* __restrict__ s_bf, float* __restrict__ lw,
    unsigned short* __restrict__ Win_bf, unsigned short* __restrict__ Wd_bf,
    unsigned short* __restrict__ Wbc_bf, int Nn)
{
    const int b = blockIdx.x, t = threadIdx.x;
    if (b < MPAD) {
        unsigned int pack = 0;
        if (b < Nn) {
            float2 sv = *(const float2*)(s + (size_t)b * 512 + t * 2);
            pack = (unsigned int)f2bf(sv.x) | ((unsigned int)f2bf(sv.y) << 16);
        }
        *(unsigned int*)(s_bf + (size_t)b * 512 + t * 2) = pack;
        if (t == 0) lw[b] = (b < Nn) ? logf(w[b] + 1e-6f) : 0.f;
    } else if (b < MPAD + 512) {
        int c = b - MPAD;
        float a0 = W_in[(size_t)c * 513 + t * 2];
        float a1 = W_in[(size_t)c * 513 + t * 2 + 1];
        *(unsigned int*)(Win_bf + (size_t)c * 512 + t * 2) =
            (unsigned int)f2bf(a0) | ((unsigned int)f2bf(a1) << 16);
    } else if (b < MPAD + 1024) {
        int c = b - MPAD - 512;
        float2 wv = *(const float2*)(W_delta + (size_t)c * 512 + t * 2);
        *(unsigned int*)(Wd_bf + (size_t)c * 512 + t * 2) =
            (unsigned int)f2bf(wv.x) | ((unsigned int)f2bf(wv.y) << 16);
    } else {
        int c = b - MPAD - 1024;   // 0..31: rows 0..15 = W_B, 16..31 = W_C
        const float* src = (c < 16) ? (W_B + (size_t)c * 512) : (W_C + (size_t)(c - 16) * 512);
        float2 wv = *(const float2*)(src + t * 2);
        *(unsigned int*)(Wbc_bf + (size_t)c * 512 + t * 2) =
            (unsigned int)f2bf(wv.x) | ((unsigned int)f2bf(wv.y) << 16);
    }
}

// ---------------- register-blocked bf16 MFMA GEMM: no LDS, no barriers ----------------
// Each wave owns a 64x64 tile. Per 32-k chunk: 8 global 16B loads + 16 MFMA.
// W (0.5 MB) is L2-resident; A streamed once (L3 catches col-strip re-reads).
// mode 0: o = z + bias[c] + lw[r]*wcol[c*wcol_stride]; store bf16 -> outbf
// mode 1: o = softplus(z+bias[c]) * sigmoid(lw[r]*wcol[c]+bw[c]); store fp32 -> outf
__global__ __launch_bounds__(256) void gemm_reg(
    const unsigned short* __restrict__ Abf,   // [16384][512] bf16
    const unsigned short* __restrict__ Wbf,   // [512][512] bf16
    float* __restrict__ outf,
    unsigned short* __restrict__ outbf,
    const float* __restrict__ bias,
    const float* __restrict__ lw,
    const float* __restrict__ wcol, int wcol_stride,
    const float* __restrict__ bw,
    int mode)
{
    const int tid = threadIdx.x;
    const int wave = tid >> 6, lane = tid & 63;
    const int row0 = (blockIdx.y * 4 + wave) * 64;   // wave-private 64-row strip
    const int col0 = blockIdx.x * 64;                // 64-col strip
    const int mrow = lane & 15;
    const int kg = (lane >> 4) * 8;                  // k-offset within 32-k chunk

    const unsigned short* Ap[4];
    const unsigned short* Bp[4];
    #pragma unroll
    for (int i = 0; i < 4; i++) {
        Ap[i] = Abf + (size_t)(row0 + i * 16 + mrow) * 512 + kg;
        Bp[i] = Wbf + (size_t)(col0 + i * 16 + mrow) * 512 + kg;
    }

    floatx4 acc[4][4] = {};

    #pragma unroll
    for (int k0 = 0; k0 < 512; k0 += 32) {
        short8 af[4], bfr[4];
        #pragma unroll
        for (int i = 0; i < 4; i++) af[i] = *(const short8*)(Ap[i] + k0);
        #pragma unroll
        for (int j = 0; j < 4; j++) bfr[j] = *(const short8*)(Bp[j] + k0);
        #pragma unroll
        for (int i = 0; i < 4; i++)
            #pragma unroll
            for (int j = 0; j < 4; j++)
                acc[i][j] = __builtin_amdgcn_mfma_f32_16x16x32_bf16(af[i], bfr[j], acc[i][j], 0, 0, 0);
    }

    // epilogue: C/D layout col=lane&15, row=(lane>>4)*4+reg
    #pragma unroll
    for (int i = 0; i < 4; i++) {
        #pragma unroll
        for (int reg = 0; reg < 4; reg++) {
            int r = row0 + i * 16 + (lane >> 4) * 4 + reg;
            float lwr = lw[r];
            #pragma unroll
            for (int j = 0; j < 4; j++) {
                int c = col0 + j * 16 + (lane & 15);
                float z = acc[i][j][reg] + bias[c];
                if (mode == 0) {
                    float o = z + lwr * wcol[(size_t)c * wcol_stride];
                    outbf[(size_t)r * 512 + c] = f2bf(o);
                } else {
                    float sp = (z > 15.f) ? z : log1pf(__expf(z));
                    float sg2 = 1.f / (1.f + __expf(-(lwr * wcol[c] + bw[c])));
                    outf[(size_t)r * 512 + c] = sp * sg2;
                }
            }
        }
    }
}

// ---------------- B/C via skinny MFMA GEMM: [16384x512] @ [512x32] ----------------
__global__ __launch_bounds__(256) void bc_gemm(
    const unsigned short* __restrict__ Abf,    // x_bf [16384][512]
    const unsigned short* __restrict__ Wbc,    // [32][512] bf16
    const float* __restrict__ b_B, const float* __restrict__ b_C,
    float* __restrict__ Bm, float* __restrict__ Cm)
{
    // register-blocked too: each wave owns 32 rows x 32 cols (B and C)
    const int tid = threadIdx.x;
    const int wave = tid >> 6, lane = tid & 63;
    const int row0 = (blockIdx.x * 4 + wave) * 32;
    const int mrow = lane & 15;
    const int kg = (lane >> 4) * 8;

    const unsigned short* Ap[2];
    const unsigned short* Bp[2];
    #pragma unroll
    for (int i = 0; i < 2; i++) {
        Ap[i] = Abf + (size_t)(row0 + i * 16 + mrow) * 512 + kg;
        Bp[i] = Wbc + (size_t)(i * 16 + mrow) * 512 + kg;
    }

    floatx4 acc[2][2] = {};
    #pragma unroll
    for (int k0 = 0; k0 < 512; k0 += 32) {
        short8 af[2], bfr[2];
        #pragma unroll
        for (int i = 0; i < 2; i++) af[i] = *(const short8*)(Ap[i] + k0);
        #pragma unroll
        for (int j = 0; j < 2; j++) bfr[j] = *(const short8*)(Bp[j] + k0);
        #pragma unroll
        for (int i = 0; i < 2; i++)
            #pragma unroll
            for (int j = 0; j < 2; j++)
                acc[i][j] = __builtin_amdgcn_mfma_f32_16x16x32_bf16(af[i], bfr[j], acc[i][j], 0, 0, 0);
    }

    const int s = lane & 15;
    #pragma unroll
    for (int i = 0; i < 2; i++) {
        #pragma unroll
        for (int reg = 0; reg < 4; reg++) {
            int r = row0 + i * 16 + (lane >> 4) * 4 + reg;
            Bm[(size_t)r * 16 + s] = acc[i][0][reg] + b_B[s];
            Cm[(size_t)r * 16 + s] = acc[i][1][reg] + b_C[s];
        }
    }
}

// fast path valid when As[s] == (s+1)*As[0]
__device__ __forceinline__ bool geo_check(const float* As) {
    bool ok = true;
    #pragma unroll
    for (int s = 1; s < 16; s++) {
        float want = (float)(s + 1) * As[0];
        ok = ok && (fabsf(As[s] - want) <= 1e-4f * (float)(s + 1));
    }
    return ok;
}

// ---------------- shallow scan (nodes 0..510, levels 0..8): walk + LN ----------------
__global__ __launch_bounds__(256) void scan_shallow(
    const unsigned short* __restrict__ x_bf, const float* __restrict__ delta,
    const float* __restrict__ Bm, const float* __restrict__ Cm,
    const float* __restrict__ A_log, const float* __restrict__ Dv,
    const float* __restrict__ gamma, const float* __restrict__ beta,
    float* __restrict__ out)
{
    const int n = blockIdx.x;
    const int t = threadIdx.x;
    const int d0 = t, d1 = t + 256;

    float As0[16], As1[16], acc0[16], acc1[16];
    #pragma unroll
    for (int s = 0; s < 16; s++) {
        As0[s] = -__expf(A_log[d0 * 16 + s]);
        As1[s] = -__expf(A_log[d1 * 16 + s]);
        acc0[s] = 0.f; acc1[s] = 0.f;
    }
    const bool fast = geo_check(As0) && geo_check(As1);

    float cum0 = 0.f, cum1 = 0.f;
    int a = n;
    while (a >= 0) {
        float da0 = delta[(size_t)a * 512 + d0];
        float da1 = delta[(size_t)a * 512 + d1];
        float bx0 = da0 * bf2f(x_bf[(size_t)a * 512 + d0]);
        float bx1 = da1 * bf2f(x_bf[(size_t)a * 512 + d1]);
        if (fast) {
            float r0 = __expf(As0[0] * cum0);
            float r1 = __expf(As1[0] * cum1);
            float pw0 = r0, pw1 = r1;
            #pragma unroll
            for (int s = 0; s < 16; s++) {
                float Bs = Bm[a * 16 + s];
                acc0[s] = fmaf(bx0 * pw0, Bs, acc0[s]);
                acc1[s] = fmaf(bx1 * pw1, Bs, acc1[s]);
                pw0 *= r0; pw1 *= r1;
            }
        } else {
            #pragma unroll
            for (int s = 0; s < 16; s++) {
                float Bs = Bm[a * 16 + s];
                acc0[s] = fmaf(bx0 * __expf(As0[s] * cum0), Bs, acc0[s]);
                acc1[s] = fmaf(bx1 * __expf(As1[s] * cum1), Bs, acc1[s]);
            }
        }
        cum0 += da0; cum1 += da1;
        a = (a - 1) >> 1;
    }

    float xn0 = bf2f(x_bf[(size_t)n * 512 + d0]);
    float xn1 = bf2f(x_bf[(size_t)n * 512 + d1]);
    float y0 = Dv[d0] * xn0, y1 = Dv[d1] * xn1;
    #pragma unroll
    for (int s = 0; s < 16; s++) {
        float Cs = Cm[(size_t)n * 16 + s];
        y0 += Cs * acc0[s];
        y1 += Cs * acc1[s];
    }

    float s1 = y0 + y1;
    float s2 = y0 * y0 + y1 * y1;
    #pragma unroll
    for (int off = 32; off > 0; off >>= 1) {
        s1 += __shfl_xor(s1, off);
        s2 += __shfl_xor(s2, off);
    }
    __shared__ float red[8];
    int wid = t >> 6, lane = t & 63;
    if (lane == 0) { red[wid] = s1; red[wid + 4] = s2; }
    __syncthreads();
    float S1 = red[0] + red[1] + red[2] + red[3];
    float S2 = red[4] + red[5] + red[6] + red[7];
    float mu = S1 * (1.f / 512.f);
    float var = S2 * (1.f / 512.f) - mu * mu;
    float inv = rsqrtf(var + 1e-5f);
    out[(size_t)n * 512 + d0] = (y0 - mu) * inv * gamma[d0] + beta[d0];
    out[(size_t)n * 512 + d1] = (y1 - mu) * inv * gamma[d1] + beta[d1];
}

// ---------------- deep scan: per level-9 subtree, fused ckpt-walk + DFS sweep + LN ----------------
__global__ __launch_bounds__(512) void scan_deep(
    const unsigned short* __restrict__ x_bf, const float* __restrict__ delta,
    const float* __restrict__ Bm, const float* __restrict__ Cm,
    const float* __restrict__ A_log, const float* __restrict__ Dv,
    const float* __restrict__ gamma, const float* __restrict__ beta,
    float* __restrict__ out)
{
    __shared__ float Y[31][512];
    __shared__ int nid[31];
    const int p = blockIdx.x;
    const int d = threadIdx.x;
    const int a9 = CKPT_BASE + p;

    float As0 = -__expf(A_log[d * 16]);
    bool fast = true;
    #pragma unroll
    for (int s = 1; s < 16; s++) {
        float As = -__expf(A_log[d * 16 + s]);
        fast = fast && (fabsf(As - (float)(s + 1) * As0) <= 1e-4f * (float)(s + 1));
    }

    // --- fused checkpoint: walk root..a9, build H9 in registers ---
    float H9v[16];
    #pragma unroll
    for (int s = 0; s < 16; s++) H9v[s] = 0.f;
    {
        float cum = 0.f;
        int a = a9;
        while (a >= 0) {
            float dlt = delta[(size_t)a * 512 + d];
            float bx = dlt * bf2f(x_bf[(size_t)a * 512 + d]);
            if (fast) {
                float r = __expf(As0 * cum);
                float pw = r;
                #pragma unroll
                for (int s = 0; s < 16; s++) {
                    H9v[s] = fmaf(bx * pw, Bm[a * 16 + s], H9v[s]);
                    pw *= r;
                }
            } else {
                #pragma unroll
                for (int s = 0; s < 16; s++) {
                    float As = -__expf(A_log[d * 16 + s]);
                    H9v[s] = fmaf(bx * __expf(As * cum), Bm[a * 16 + s], H9v[s]);
                }
            }
            cum += dlt;
            a = (a - 1) >> 1;
        }
    }

    // root (level-9 node) readout directly from H9v
    {
        float xv = bf2f(x_bf[(size_t)a9 * 512 + d]);
        float y = Dv[d] * xv;
        #pragma unroll
        for (int s = 0; s < 16; s++) y = fmaf(Cm[(size_t)a9 * 16 + s], H9v[s], y);
        Y[0][d] = y;
        if (d == 0) nid[0] = a9;
    }

    auto step = [&](int n, const float* Hp, float* Hc, int slot) {
        float dlt = delta[(size_t)n * 512 + d];
        float xv = bf2f(x_bf[(size_t)n * 512 + d]);
        float bx = dlt * xv;
        const float* Bn = Bm + (size_t)n * 16;
        const float* Cn = Cm + (size_t)n * 16;
        float y = Dv[d] * xv;
        if (fast) {
            float r = __expf(As0 * dlt);
            float pw = r;
            #pragma unroll
            for (int s = 0; s < 16; s++) {
                Hc[s] = fmaf(pw, Hp[s], bx * Bn[s]);
                y = fmaf(Cn[s], Hc[s], y);
                pw *= r;
            }
        } else {
            #pragma unroll
            for (int s = 0; s < 16; s++) {
                float Ab = __expf(dlt * (-__expf(A_log[d * 16 + s])));
                Hc[s] = fmaf(Ab, Hp[s], bx * Bn[s]);
                y = fmaf(Cn[s], Hc[s], y);
            }
        }
        Y[slot][d] = y;
        if (d == 0) nid[slot] = n;
    };

    float H10[16], H11[16], H12[16], H13[16];
    int slot = 1;
    #pragma unroll
    for (int c0 = 0; c0 < 2; c0++) {
        int n10 = 2 * a9 + 1 + c0;
        step(n10, H9v, H10, slot++);
        #pragma unroll
        for (int c1 = 0; c1 < 2; c1++) {
            int n11 = 2 * n10 + 1 + c1;
            step(n11, H10, H11, slot++);
            #pragma unroll
            for (int c2 = 0; c2 < 2; c2++) {
                int n12 = 2 * n11 + 1 + c2;
                step(n12, H11, H12, slot++);
                #pragma unroll
                for (int c3 = 0; c3 < 2; c3++) {
                    int n13 = 2 * n12 + 1 + c3;
                    step(n13, H12, H13, slot++);
                }
            }
        }
    }
    __syncthreads();

    const int w = d >> 6, lane = d & 63;
    for (int i = w; i < 31; i += 8) {
        int n = nid[i];
        float v[8]; float s1 = 0.f, s2 = 0.f;
        #pragma unroll
        for (int k = 0; k < 8; k++) {
            v[k] = Y[i][lane + 64 * k];
            s1 += v[k]; s2 += v[k] * v[k];
        }
        #pragma unroll
        for (int off = 32; off > 0; off >>= 1) {
            s1 += __shfl_xor(s1, off);
            s2 += __shfl_xor(s2, off);
        }
        float mu = s1 * (1.f / 512.f);
        float inv = rsqrtf(s2 * (1.f / 512.f) - mu * mu + 1e-5f);
        #pragma unroll
        for (int k = 0; k < 8; k++) {
            int ch = lane + 64 * k;
            out[(size_t)n * 512 + ch] = (v[k] - mu) * inv * gamma[ch] + beta[ch];
        }
    }
}

extern "C" void kernel_launch(void* const* d_in, const int* in_sizes, int n_in,
                              void* d_out, int out_size, void* d_ws, size_t ws_size,
                              hipStream_t stream) {
    const float* s_in   = (const float*)d_in[0];
    const float* w      = (const float*)d_in[1];
    const float* W_in    = (const float*)d_in[4];
    const float* b_in    = (const float*)d_in[5];
    const float* W_delta = (const float*)d_in[6];
    const float* b_delta = (const float*)d_in[7];
    const float* W_w     = (const float*)d_in[8];
    const float* b_w     = (const float*)d_in[9];
    const float* A_log   = (const float*)d_in[10];
    const float* Dv      = (const float*)d_in[11];
    const float* W_B     = (const float*)d_in[12];
    const float* b_B     = (const float*)d_in[13];
    const float* W_C     = (const float*)d_in[14];
    const float* b_C     = (const float*)d_in[15];
    const float* gamma   = (const float*)d_in[16];
    const float* beta    = (const float*)d_in[17];
    float* out = (float*)d_out;

    const int Nn = in_sizes[1];           // 16383

    float* ws    = (float*)d_ws;
    float* lw    = ws;                                      // 16384
    float* delta = lw + MPAD;                               // 16384*512 fp32
    float* Bm    = delta + (size_t)MPAD * 512;              // 16384*16
    float* Cm    = Bm + (size_t)MPAD * 16;                  // 16384*16
    unsigned short* s_bf  = (unsigned short*)(Cm + (size_t)MPAD * 16);  // 16384*512
    unsigned short* x_bf  = s_bf + (size_t)MPAD * 512;      // 16384*512
    unsigned short* Win_bf = x_bf + (size_t)MPAD * 512;     // 512*512
    unsigned short* Wd_bf  = Win_bf + 512 * 512;            // 512*512
    unsigned short* Wbc_bf = Wd_bf + 512 * 512;             // 32*512

    prep_kernel<<<MPAD + 1024 + 32, 256, 0, stream>>>(s_in, w, W_in, W_delta, W_B, W_C,
                                                      s_bf, lw, Win_bf, Wd_bf, Wbc_bf, Nn);

    dim3 gg(8, 64);   // 64-col strips x (4 waves * 64 rows) -> 512 blocks, wave-independent
    gemm_reg<<<gg, 256, 0, stream>>>(s_bf, Win_bf, nullptr, x_bf,
                                     b_in, lw, W_in + 512, 513, nullptr, 0);
    gemm_reg<<<gg, 256, 0, stream>>>(x_bf, Wd_bf, delta, nullptr,
                                     b_delta, lw, W_w, 1, b_w, 1);

    bc_gemm<<<128, 256, 0, stream>>>(x_bf, Wbc_bf, b_B, b_C, Bm, Cm);

    scan_shallow<<<CKPT_BASE, 256, 0, stream>>>(x_bf, delta, Bm, Cm, A_log, Dv,
                                                gamma, beta, out);

    scan_deep<<<N_CKPT, 512, 0, stream>>>(x_bf, delta, Bm, Cm, A_log, Dv,
                                          gamma, beta, out);
}

// Round 10
// 263.900 us; speedup vs baseline: 1.1569x; 1.1569x over previous
//
#include <hip/hip_runtime.h>
#include <hip/hip_bf16.h>
#include <math.h>

#define D_SSM 512
#define D_STATE 16
#define L10_BASE 1023     // first index of level 10
#define N_L10 1024        // nodes at level 10
#define MPAD 16384

typedef __attribute__((ext_vector_type(8))) short short8;
typedef __attribute__((ext_vector_type(4))) float floatx4;

__device__ __forceinline__ unsigned short f2bf(float f) {
    unsigned int u = __float_as_uint(f);
    unsigned int r = (u + 0x7fffu + ((u >> 16) & 1u)) >> 16;
    return (unsigned short)r;
}
__device__ __forceinline__ float bf2f(unsigned short u) {
    return __uint_as_float(((unsigned int)u) << 16);
}
__device__ __forceinline__ void g2lds16(const void* g, void* l) {
    __builtin_amdgcn_global_load_lds(
        (const __attribute__((address_space(1))) void*)g,
        (__attribute__((address_space(3))) void*)l, 16, 0, 0);
}

// ---------------- prep: cast s/W_in/W_delta/W_B/W_C to bf16, compute lw ----------------
__global__ __launch_bounds__(256) void prep_kernel(
    const float* __restrict__ s, const float* __restrict__ w,
    const float* __restrict__ W_in, const float* __restrict__ W_delta,
    const float* __restrict__ W_B, const float* __restrict__ W_C,
    unsigned short* __restrict__ s_bf, float* __restrict__ lw,
    unsigned short* __restrict__ Win_bf, unsigned short* __restrict__ Wd_bf,
    unsigned short* __restrict__ Wbc_bf, int Nn)
{
    const int b = blockIdx.x, t = threadIdx.x;
    if (b < MPAD) {
        unsigned int pack = 0;
        if (b < Nn) {
            float2 sv = *(const float2*)(s + (size_t)b * 512 + t * 2);
            pack = (unsigned int)f2bf(sv.x) | ((unsigned int)f2bf(sv.y) << 16);
        }
        *(unsigned int*)(s_bf + (size_t)b * 512 + t * 2) = pack;
        if (t == 0) lw[b] = (b < Nn) ? logf(w[b] + 1e-6f) : 0.f;
    } else if (b < MPAD + 512) {
        int c = b - MPAD;
        float a0 = W_in[(size_t)c * 513 + t * 2];
        float a1 = W_in[(size_t)c * 513 + t * 2 + 1];
        *(unsigned int*)(Win_bf + (size_t)c * 512 + t * 2) =
            (unsigned int)f2bf(a0) | ((unsigned int)f2bf(a1) << 16);
    } else if (b < MPAD + 1024) {
        int c = b - MPAD - 512;
        float2 wv = *(const float2*)(W_delta + (size_t)c * 512 + t * 2);
        *(unsigned int*)(Wd_bf + (size_t)c * 512 + t * 2) =
            (unsigned int)f2bf(wv.x) | ((unsigned int)f2bf(wv.y) << 16);
    } else {
        int c = b - MPAD - 1024;   // 0..31: rows 0..15 = W_B, 16..31 = W_C
        const float* src = (c < 16) ? (W_B + (size_t)c * 512) : (W_C + (size_t)(c - 16) * 512);
        float2 wv = *(const float2*)(src + t * 2);
        *(unsigned int*)(Wbc_bf + (size_t)c * 512 + t * 2) =
            (unsigned int)f2bf(wv.x) | ((unsigned int)f2bf(wv.y) << 16);
    }
}

// ---------------- bf16 MFMA GEMM, 64x128 tile, BK=32, double-buffered LDS (r6 config) ----------------
// mode 0: o = z + bias[c] + lw[r]*wcol[c*wcol_stride]; store bf16 -> outbf
// mode 1: o = softplus(z+bias[c]) * sigmoid(lw[r]*wcol[c]+bw[c]); store fp32 -> outf
__global__ __launch_bounds__(256) void gemm_mfma(
    const unsigned short* __restrict__ Abf,   // [16384][512] bf16
    const unsigned short* __restrict__ Wbf,   // [512][512] bf16
    float* __restrict__ outf,
    unsigned short* __restrict__ outbf,
    const float* __restrict__ bias,
    const float* __restrict__ lw,
    const float* __restrict__ wcol, int wcol_stride,
    const float* __restrict__ bw,
    int mode)
{
    __shared__ __align__(16) short As[2][64 * 32];    // 4 KB per buffer
    __shared__ __align__(16) short Bs[2][128 * 32];   // 8 KB per buffer
    const int tid = threadIdx.x;
    const int wave = tid >> 6, lane = tid & 63;
    const int row0 = blockIdx.y * 64;
    const int col0 = blockIdx.x * 128;
    const int wr = (wave >> 1) * 32;     // wave's 32-row strip
    const int wc = (wave & 1) * 64;      // wave's 64-col strip

    floatx4 acc[2][4] = {};

    const int srow = lane >> 2;                       // 0..15
    const int sg   = (lane & 3) ^ ((srow >> 1) & 3);  // XOR swizzle
    const int scol = sg * 8;

    const unsigned short* Ag = Abf + (size_t)(row0 + wave * 16 + srow) * 512 + scol;
    const unsigned short* Wg0 = Wbf + (size_t)(col0 + (wave * 2 + 0) * 16 + srow) * 512 + scol;
    const unsigned short* Wg1 = Wbf + (size_t)(col0 + (wave * 2 + 1) * 16 + srow) * 512 + scol;

    {   // stage k-chunk 0 into buffer 0
        g2lds16(Ag, (char*)&As[0][0] + wave * 1024);
        g2lds16(Wg0, (char*)&Bs[0][0] + (wave * 2 + 0) * 1024);
        g2lds16(Wg1, (char*)&Bs[0][0] + (wave * 2 + 1) * 1024);
    }
    __syncthreads();

    for (int it = 0; it < 16; it++) {
        const int cur = it & 1;
        if (it < 15) {   // prefetch next chunk into the other buffer
            int k1 = (it + 1) * 32;
            g2lds16(Ag + k1, (char*)&As[cur ^ 1][0] + wave * 1024);
            g2lds16(Wg0 + k1, (char*)&Bs[cur ^ 1][0] + (wave * 2 + 0) * 1024);
            g2lds16(Wg1 + k1, (char*)&Bs[cur ^ 1][0] + (wave * 2 + 1) * 1024);
        }

        short8 af[2], bfr[4];
        #pragma unroll
        for (int i = 0; i < 2; i++) {
            int m = wr + i * 16 + (lane & 15);
            int gm = (lane >> 4) ^ ((m >> 1) & 3);
            af[i] = *(const short8*)&As[cur][m * 32 + gm * 8];
        }
        #pragma unroll
        for (int j = 0; j < 4; j++) {
            int n = wc + j * 16 + (lane & 15);
            int gn = (lane >> 4) ^ ((n >> 1) & 3);
            bfr[j] = *(const short8*)&Bs[cur][n * 32 + gn * 8];
        }
        #pragma unroll
        for (int i = 0; i < 2; i++)
            #pragma unroll
            for (int j = 0; j < 4; j++)
                acc[i][j] = __builtin_amdgcn_mfma_f32_16x16x32_bf16(af[i], bfr[j], acc[i][j], 0, 0, 0);
        __syncthreads();
    }

    // epilogue: C/D layout col=lane&15, row=(lane>>4)*4+reg
    #pragma unroll
    for (int i = 0; i < 2; i++) {
        #pragma unroll
        for (int reg = 0; reg < 4; reg++) {
            int r = row0 + wr + i * 16 + (lane >> 4) * 4 + reg;
            float lwr = lw[r];
            #pragma unroll
            for (int j = 0; j < 4; j++) {
                int c = col0 + wc + j * 16 + (lane & 15);
                float z = acc[i][j][reg] + bias[c];
                if (mode == 0) {
                    float o = z + lwr * wcol[(size_t)c * wcol_stride];
                    outbf[(size_t)r * 512 + c] = f2bf(o);
                } else {
                    float sp = (z > 15.f) ? z : log1pf(__expf(z));
                    float sg2 = 1.f / (1.f + __expf(-(lwr * wcol[c] + bw[c])));
                    outf[(size_t)r * 512 + c] = sp * sg2;
                }
            }
        }
    }
}

// ---------------- B/C via skinny MFMA GEMM: [16384x512] @ [512x32] ----------------
__global__ __launch_bounds__(256) void bc_gemm(
    const unsigned short* __restrict__ Abf,    // x_bf [16384][512]
    const unsigned short* __restrict__ Wbc,    // [32][512] bf16
    const float* __restrict__ b_B, const float* __restrict__ b_C,
    float* __restrict__ Bm, float* __restrict__ Cm)
{
    __shared__ __align__(16) short As[128 * 32];
    __shared__ __align__(16) short Ws[32 * 512];
    const int tid = threadIdx.x;
    const int wave = tid >> 6, lane = tid & 63;
    const int row0 = blockIdx.x * 128;
    const int wr = wave * 32;

    for (int i = 0; i < 8; i++) {
        int fg = i * 256 + tid;          // flat k-group id, 0..2047
        int n = fg >> 6, kgg = fg & 63;
        short8 v = *(const short8*)(Wbc + (size_t)n * 512 + kgg * 8);
        *(short8*)&Ws[n * 512 + ((kgg ^ (n & 7)) * 8)] = v;
    }

    floatx4 acc[2][2] = {};

    const int srow = lane >> 2;
    const int sgz  = (lane & 3) ^ ((srow >> 1) & 3);
    const int scol = sgz * 8;

    for (int k0 = 0; k0 < 512; k0 += 32) {
        #pragma unroll
        for (int j = 0; j < 2; j++) {
            int c = wave * 2 + j;
            int r = c * 16 + srow;
            g2lds16(Abf + (size_t)(row0 + r) * 512 + k0 + scol, (char*)As + c * 1024);
        }
        __syncthreads();

        short8 af[2], bfr[2];
        #pragma unroll
        for (int i = 0; i < 2; i++) {
            int m = wr + i * 16 + (lane & 15);
            int gm = (lane >> 4) ^ ((m >> 1) & 3);
            af[i] = *(const short8*)&As[m * 32 + gm * 8];
        }
        #pragma unroll
        for (int j = 0; j < 2; j++) {
            int n = j * 16 + (lane & 15);
            int Gg = (k0 >> 3) + (lane >> 4);
            bfr[j] = *(const short8*)&Ws[n * 512 + ((Gg ^ (n & 7)) * 8)];
        }
        #pragma unroll
        for (int i = 0; i < 2; i++)
            #pragma unroll
            for (int j = 0; j < 2; j++)
                acc[i][j] = __builtin_amdgcn_mfma_f32_16x16x32_bf16(af[i], bfr[j], acc[i][j], 0, 0, 0);
        __syncthreads();
    }

    const int s = lane & 15;
    #pragma unroll
    for (int i = 0; i < 2; i++) {
        #pragma unroll
        for (int reg = 0; reg < 4; reg++) {
            int r = row0 + wr + i * 16 + (lane >> 4) * 4 + reg;
            Bm[(size_t)r * 16 + s] = acc[i][0][reg] + b_B[s];
            Cm[(size_t)r * 16 + s] = acc[i][1][reg] + b_C[s];
        }
    }
}

// fast path valid when As[s] == (s+1)*As[0]
__device__ __forceinline__ bool geo_check(const float* As) {
    bool ok = true;
    #pragma unroll
    for (int s = 1; s < 16; s++) {
        float want = (float)(s + 1) * As[0];
        ok = ok && (fabsf(As[s] - want) <= 1e-4f * (float)(s + 1));
    }
    return ok;
}

// ---------------- shallow scan (nodes 0..1022, levels 0..9): walk + LN ----------------
__global__ __launch_bounds__(256) void scan_shallow(
    const unsigned short* __restrict__ x_bf, const float* __restrict__ delta,
    const float* __restrict__ Bm, const float* __restrict__ Cm,
    const float* __restrict__ A_log, const float* __restrict__ Dv,
    const float* __restrict__ gamma, const float* __restrict__ beta,
    float* __restrict__ out)
{
    const int n = blockIdx.x;
    const int t = threadIdx.x;
    const int d0 = t, d1 = t + 256;

    float As0[16], As1[16], acc0[16], acc1[16];
    #pragma unroll
    for (int s = 0; s < 16; s++) {
        As0[s] = -__expf(A_log[d0 * 16 + s]);
        As1[s] = -__expf(A_log[d1 * 16 + s]);
        acc0[s] = 0.f; acc1[s] = 0.f;
    }
    const bool fast = geo_check(As0) && geo_check(As1);

    float cum0 = 0.f, cum1 = 0.f;
    int a = n;
    while (a >= 0) {
        float da0 = delta[(size_t)a * 512 + d0];
        float da1 = delta[(size_t)a * 512 + d1];
        float bx0 = da0 * bf2f(x_bf[(size_t)a * 512 + d0]);
        float bx1 = da1 * bf2f(x_bf[(size_t)a * 512 + d1]);
        if (fast) {
            float r0 = __expf(As0[0] * cum0);
            float r1 = __expf(As1[0] * cum1);
            float pw0 = r0, pw1 = r1;
            #pragma unroll
            for (int s = 0; s < 16; s++) {
                float Bs = Bm[a * 16 + s];
                acc0[s] = fmaf(bx0 * pw0, Bs, acc0[s]);
                acc1[s] = fmaf(bx1 * pw1, Bs, acc1[s]);
                pw0 *= r0; pw1 *= r1;
            }
        } else {
            #pragma unroll
            for (int s = 0; s < 16; s++) {
                float Bs = Bm[a * 16 + s];
                acc0[s] = fmaf(bx0 * __expf(As0[s] * cum0), Bs, acc0[s]);
                acc1[s] = fmaf(bx1 * __expf(As1[s] * cum1), Bs, acc1[s]);
            }
        }
        cum0 += da0; cum1 += da1;
        a = (a - 1) >> 1;
    }

    float xn0 = bf2f(x_bf[(size_t)n * 512 + d0]);
    float xn1 = bf2f(x_bf[(size_t)n * 512 + d1]);
    float y0 = Dv[d0] * xn0, y1 = Dv[d1] * xn1;
    #pragma unroll
    for (int s = 0; s < 16; s++) {
        float Cs = Cm[(size_t)n * 16 + s];
        y0 += Cs * acc0[s];
        y1 += Cs * acc1[s];
    }

    float s1 = y0 + y1;
    float s2 = y0 * y0 + y1 * y1;
    #pragma unroll
    for (int off = 32; off > 0; off >>= 1) {
        s1 += __shfl_xor(s1, off);
        s2 += __shfl_xor(s2, off);
    }
    __shared__ float red[8];
    int wid = t >> 6, lane = t & 63;
    if (lane == 0) { red[wid] = s1; red[wid + 4] = s2; }
    __syncthreads();
    float S1 = red[0] + red[1] + red[2] + red[3];
    float S2 = red[4] + red[5] + red[6] + red[7];
    float mu = S1 * (1.f / 512.f);
    float var = S2 * (1.f / 512.f) - mu * mu;
    float inv = rsqrtf(var + 1e-5f);
    out[(size_t)n * 512 + d0] = (y0 - mu) * inv * gamma[d0] + beta[d0];
    out[(size_t)n * 512 + d1] = (y1 - mu) * inv * gamma[d1] + beta[d1];
}

// ---------------- deep scan: one block per level-10 node ----------------
// walk 11 ancestors (reg H10), DFS 14 descendants (levels 11..13), LN for 15 nodes.
// LDS 30 KB -> ~4 blocks/CU (vs 63.5 KB / 2 blocks at the level-9 split).
__global__ __launch_bounds__(512) void scan_deep(
    const unsigned short* __restrict__ x_bf, const float* __restrict__ delta,
    const float* __restrict__ Bm, const float* __restrict__ Cm,
    const float* __restrict__ A_log, const float* __restrict__ Dv,
    const float* __restrict__ gamma, const float* __restrict__ beta,
    float* __restrict__ out)
{
    __shared__ float Y[15][512];
    __shared__ int nid[15];
    const int p = blockIdx.x;
    const int d = threadIdx.x;
    const int a10 = L10_BASE + p;

    float As0 = -__expf(A_log[d * 16]);
    bool fast = true;
    #pragma unroll
    for (int s = 1; s < 16; s++) {
        float As = -__expf(A_log[d * 16 + s]);
        fast = fast && (fabsf(As - (float)(s + 1) * As0) <= 1e-4f * (float)(s + 1));
    }

    // --- walk node..root building H(a10) in registers ---
    float H10v[16];
    #pragma unroll
    for (int s = 0; s < 16; s++) H10v[s] = 0.f;
    {
        float cum = 0.f;
        int a = a10;
        while (a >= 0) {
            float dlt = delta[(size_t)a * 512 + d];
            float bx = dlt * bf2f(x_bf[(size_t)a * 512 + d]);
            if (fast) {
                float r = __expf(As0 * cum);
                float pw = r;
                #pragma unroll
                for (int s = 0; s < 16; s++) {
                    H10v[s] = fmaf(bx * pw, Bm[a * 16 + s], H10v[s]);
                    pw *= r;
                }
            } else {
                #pragma unroll
                for (int s = 0; s < 16; s++) {
                    float As = -__expf(A_log[d * 16 + s]);
                    H10v[s] = fmaf(bx * __expf(As * cum), Bm[a * 16 + s], H10v[s]);
                }
            }
            cum += dlt;
            a = (a - 1) >> 1;
        }
    }

    // self readout
    {
        float xv = bf2f(x_bf[(size_t)a10 * 512 + d]);
        float y = Dv[d] * xv;
        #pragma unroll
        for (int s = 0; s < 16; s++) y = fmaf(Cm[(size_t)a10 * 16 + s], H10v[s], y);
        Y[0][d] = y;
        if (d == 0) nid[0] = a10;
    }

    auto step = [&](int n, const float* Hp, float* Hc, int slot) {
        float dlt = delta[(size_t)n * 512 + d];
        float xv = bf2f(x_bf[(size_t)n * 512 + d]);
        float bx = dlt * xv;
        const float* Bn = Bm + (size_t)n * 16;
        const float* Cn = Cm + (size_t)n * 16;
        float y = Dv[d] * xv;
        if (fast) {
            float r = __expf(As0 * dlt);
            float pw = r;
            #pragma unroll
            for (int s = 0; s < 16; s++) {
                Hc[s] = fmaf(pw, Hp[s], bx * Bn[s]);
                y = fmaf(Cn[s], Hc[s], y);
                pw *= r;
            }
        } else {
            #pragma unroll
            for (int s = 0; s < 16; s++) {
                float Ab = __expf(dlt * (-__expf(A_log[d * 16 + s])));
                Hc[s] = fmaf(Ab, Hp[s], bx * Bn[s]);
                y = fmaf(Cn[s], Hc[s], y);
            }
        }
        Y[slot][d] = y;
        if (d == 0) nid[slot] = n;
    };

    float H11[16], H12[16], H13[16];
    int slot = 1;
    #pragma unroll
    for (int c0 = 0; c0 < 2; c0++) {
        int n11 = 2 * a10 + 1 + c0;
        step(n11, H10v, H11, slot++);
        #pragma unroll
        for (int c1 = 0; c1 < 2; c1++) {
            int n12 = 2 * n11 + 1 + c1;
            step(n12, H11, H12, slot++);
            #pragma unroll
            for (int c2 = 0; c2 < 2; c2++) {
                int n13 = 2 * n12 + 1 + c2;
                step(n13, H12, H13, slot++);
            }
        }
    }
    __syncthreads();

    const int w = d >> 6, lane = d & 63;
    for (int i = w; i < 15; i += 8) {
        int n = nid[i];
        float v[8]; float s1 = 0.f, s2 = 0.f;
        #pragma unroll
        for (int k = 0; k < 8; k++) {
            v[k] = Y[i][lane + 64 * k];
            s1 += v[k]; s2 += v[k] * v[k];
        }
        #pragma unroll
        for (int off = 32; off > 0; off >>= 1) {
            s1 += __shfl_xor(s1, off);
            s2 += __shfl_xor(s2, off);
        }
        float mu = s1 * (1.f / 512.f);
        float inv = rsqrtf(s2 * (1.f / 512.f) - mu * mu + 1e-5f);
        #pragma unroll
        for (int k = 0; k < 8; k++) {
            int ch = lane + 64 * k;
            out[(size_t)n * 512 + ch] = (v[k] - mu) * inv * gamma[ch] + beta[ch];
        }
    }
}

extern "C" void kernel_launch(void* const* d_in, const int* in_sizes, int n_in,
                              void* d_out, int out_size, void* d_ws, size_t ws_size,
                              hipStream_t stream) {
    const float* s_in   = (const float*)d_in[0];
    const float* w      = (const float*)d_in[1];
    const float* W_in    = (const float*)d_in[4];
    const float* b_in    = (const float*)d_in[5];
    const float* W_delta = (const float*)d_in[6];
    const float* b_delta = (const float*)d_in[7];
    const float* W_w     = (const float*)d_in[8];
    const float* b_w     = (const float*)d_in[9];
    const float* A_log   = (const float*)d_in[10];
    const float* Dv      = (const float*)d_in[11];
    const float* W_B     = (const float*)d_in[12];
    const float* b_B     = (const float*)d_in[13];
    const float* W_C     = (const float*)d_in[14];
    const float* b_C     = (const float*)d_in[15];
    const float* gamma   = (const float*)d_in[16];
    const float* beta    = (const float*)d_in[17];
    float* out = (float*)d_out;

    const int Nn = in_sizes[1];           // 16383

    float* ws    = (float*)d_ws;
    float* lw    = ws;                                      // 16384
    float* delta = lw + MPAD;                               // 16384*512 fp32
    float* Bm    = delta + (size_t)MPAD * 512;              // 16384*16
    float* Cm    = Bm + (size_t)MPAD * 16;                  // 16384*16
    unsigned short* s_bf  = (unsigned short*)(Cm + (size_t)MPAD * 16);  // 16384*512
    unsigned short* x_bf  = s_bf + (size_t)MPAD * 512;      // 16384*512
    unsigned short* Win_bf = x_bf + (size_t)MPAD * 512;     // 512*512
    unsigned short* Wd_bf  = Win_bf + 512 * 512;            // 512*512
    unsigned short* Wbc_bf = Wd_bf + 512 * 512;             // 32*512

    prep_kernel<<<MPAD + 1024 + 32, 256, 0, stream>>>(s_in, w, W_in, W_delta, W_B, W_C,
                                                      s_bf, lw, Win_bf, Wd_bf, Wbc_bf, Nn);

    dim3 gg(4, 256);   // 128-col x 64-row tiles -> 1024 blocks
    gemm_mfma<<<gg, 256, 0, stream>>>(s_bf, Win_bf, nullptr, x_bf,
                                      b_in, lw, W_in + 512, 513, nullptr, 0);
    gemm_mfma<<<gg, 256, 0, stream>>>(x_bf, Wd_bf, delta, nullptr,
                                      b_delta, lw, W_w, 1, b_w, 1);

    bc_gemm<<<128, 256, 0, stream>>>(x_bf, Wbc_bf, b_B, b_C, Bm, Cm);

    scan_shallow<<<L10_BASE, 256, 0, stream>>>(x_bf, delta, Bm, Cm, A_log, Dv,
                                               gamma, beta, out);

    scan_deep<<<N_L10, 512, 0, stream>>>(x_bf, delta, Bm, Cm, A_log, Dv,
                                         gamma, beta, out);
}